// Round 10
// baseline (14030.269 us; speedup 1.0000x reference)
//
#include <hip/hip_runtime.h>
#include <math.h>

#define T_LEN 1500
#define DM 256
#define DI 64
#define MEMN 10
#define SYNCD 528
#define VOC 15

typedef _Float16 f16;
typedef _Float16 f16x2 __attribute__((ext_vector_type(2)));
typedef _Float16 f16x8 __attribute__((ext_vector_type(8)));

#define FDOT2(a, b, c) __builtin_amdgcn_fdot2((a), (b), (c), false)

static __device__ __forceinline__ float dot8(f16x8 w, f16x8 q, float acc) {
  acc = FDOT2(__builtin_shufflevector(w, w, 0, 1), __builtin_shufflevector(q, q, 0, 1), acc);
  acc = FDOT2(__builtin_shufflevector(w, w, 2, 3), __builtin_shufflevector(q, q, 2, 3), acc);
  acc = FDOT2(__builtin_shufflevector(w, w, 4, 5), __builtin_shufflevector(q, q, 4, 5), acc);
  acc = FDOT2(__builtin_shufflevector(w, w, 6, 7), __builtin_shufflevector(q, q, 6, 7), acc);
  return acc;
}
static __device__ __forceinline__ f16x2 pack2(float a, float b) {
  f16x2 r; r.x = (_Float16)a; r.y = (_Float16)b; return r;
}
static __device__ __forceinline__ float sigm(float x) { return 1.0f / (1.0f + __expf(-x)); }

// ---- DPP cross-lane ----
#define DPP_TERM(x, ctrl, rmask) \
  __int_as_float(__builtin_amdgcn_update_dpp(0, __float_as_int(x), (ctrl), (rmask), 0xF, true))
#define DPPADD(x, ctrl, rmask) (x) += DPP_TERM(x, ctrl, rmask)
// full 64-lane sum of a and b; valid in lane 63
#define WSUM2(a, b) do { \
  DPPADD(a, 0x111, 0xF); DPPADD(b, 0x111, 0xF); \
  DPPADD(a, 0x112, 0xF); DPPADD(b, 0x112, 0xF); \
  DPPADD(a, 0x114, 0xF); DPPADD(b, 0x114, 0xF); \
  DPPADD(a, 0x118, 0xF); DPPADD(b, 0x118, 0xF); \
  DPPADD(a, 0x142, 0xA); DPPADD(b, 0x142, 0xA); \
  DPPADD(a, 0x143, 0xC); DPPADD(b, 0x143, 0xC); \
} while (0)
// octet (8-lane) total into all 8 lanes: xor1, xor2 (quad_perm), then half-mirror cross-quad
#define OSUM(x) do { DPPADD(x, 0xB1, 0xF); DPPADD(x, 0x4E, 0xF); DPPADD(x, 0x141, 0xF); } while (0)
static __device__ __forceinline__ float readlane_f(float x, int l) {
  return __int_as_float(__builtin_amdgcn_readlane(__float_as_int(x), l));
}

struct Params {
  const float *x, *st0, *ast0, *Wb, *bb, *Wf, *bf, *gf, *bef,
              *Wd, *bd, *gd, *bed, *Wu, *bu, *gu, *beu, *gs, *bes,
              *w1, *b1, *w2, *b2, *Wh, *bh;
  const f16* wf16;
  float* out;
};

struct Smem {
  float4 W1v[MEMN * DM];
  float4 W2v[DM];
  float4 B1v[DM];
  float2 B2v[DM];
  float Bf[2 * DM];
  float Bu[2 * DM];
  float Bd[32];
  float Gf[DM], Bef[DM], Gu[DM], Beu[DM], Gs[DM], Bes[DM];
  float Gd[16], Bed[16];
  float Bh[16];
  float Bb[DI];
  float PC1[32], PC2[32];       // LN-fold tables: sum_k Bef_k*Wd[k][j], sum_k Gf_k*Wd[k][j]
  __attribute__((aligned(16))) float St[MEMN * DM];
  __attribute__((aligned(16))) float G[DM];           // ghat = g*Gf
  float Act[DM];
  __attribute__((aligned(16))) float D1[16];
  float X2[2][DI];
  __attribute__((aligned(16))) f16x2 Pre2[160];       // permuted pre layout (see wf16_kernel)
  float PartD[16 * 33];
  float PartK[512];
  float PartH[240];
  float2 RedAB[8];
  float2 Red2AB[8];
  float Prod[SYNCD];
  float WhL[SYNCD * VOC];
  int Pair[SYNCD];
};

// Wf f32 [k][col] -> f16 chunk-major [nk/8][col][nk%8], K-rows PERMUTED so that the
// act part of `pre` can be written barrier-free:
//   k < 64 (kv): nk = k
//   k >= 64 (act channel ch=k-64, ch = mc + 64*j): nk = 64 + 2*mc + 128*(j>>1) + (j&1)
// => f16x2 word 32+mc+64*b of Pre2 holds (act[mc+128b], act[mc+64+128b]).
__global__ __launch_bounds__(512) void wf16_kernel(const float* __restrict__ Wf,
                                                   f16* __restrict__ out) {
  int k = blockIdx.x;          // 0..319
  int c = threadIdx.x;         // 0..511
  int nk;
  if (k < 64) nk = k;
  else { int ch = k - 64; int mc = ch & 63; int j = ch >> 6;
         nk = 64 + 2 * mc + 128 * (j >> 1) + (j & 1); }
  out[((size_t)(nk >> 3) * 512 + (size_t)c) * 8 + (nk & 7)] = (f16)Wf[(size_t)k * 512 + c];
}

#define FOR8K(X) X(0) X(1) X(2) X(3) X(4) X(5) X(6) X(7)
#define DECLW(K) f16x8 w##K##_0, w##K##_1, w##K##_2, w##K##_3, w##K##_4;
#define LOADW(K) { size_t cb = (size_t)(mc + 64 * (K)); \
  w##K##_0 = wf8[(size_t)(5 * o + 0) * 512 + cb]; \
  w##K##_1 = wf8[(size_t)(5 * o + 1) * 512 + cb]; \
  w##K##_2 = wf8[(size_t)(5 * o + 2) * 512 + cb]; \
  w##K##_3 = wf8[(size_t)(5 * o + 3) * 512 + cb]; \
  w##K##_4 = wf8[(size_t)(5 * o + 4) * 512 + cb]; }
#define DOTJ(J) { f16x8 q_ = pr8[5 * o + (J)]; \
  ac0 = dot8(w0_##J, q_, ac0); ac1 = dot8(w1_##J, q_, ac1); \
  ac2 = dot8(w2_##J, q_, ac2); ac3 = dot8(w3_##J, q_, ac3); \
  ac4 = dot8(w4_##J, q_, ac4); ac5 = dot8(w5_##J, q_, ac5); \
  ac6 = dot8(w6_##J, q_, ac6); ac7 = dot8(w7_##J, q_, ac7); }

__global__ __launch_bounds__(512) __attribute__((amdgpu_waves_per_eu(2, 2)))
void ctm_kernel(Params P) {
  const int tid = threadIdx.x;
  const int b = blockIdx.x;
  __shared__ Smem sm_s;
  Smem* sm = &sm_s;

  // ---------------- LDS preload (once) ----------------
  for (int i = tid; i < MEMN * DM; i += 512) sm->W1v[i] = ((const float4*)P.w1)[i];
  if (tid < DM) {
    float2 a = ((const float2*)P.w2)[tid];
    float2 c = ((const float2*)P.w2)[DM + tid];
    float4 w; w.x = a.x; w.y = a.y; w.z = c.x; w.w = c.y;
    sm->W2v[tid] = w;
    sm->B1v[tid] = ((const float4*)P.b1)[tid];
    sm->B2v[tid] = ((const float2*)P.b2)[tid];
    sm->Gf[tid] = P.gf[tid]; sm->Bef[tid] = P.bef[tid];
    sm->Gu[tid] = P.gu[tid]; sm->Beu[tid] = P.beu[tid];
    sm->Gs[tid] = P.gs[tid]; sm->Bes[tid] = P.bes[tid];
  }
  sm->Bf[tid] = P.bf[tid];
  sm->Bu[tid] = P.bu[tid];
  if (tid < 32) sm->Bd[tid] = P.bd[tid];
  if (tid < 16) { sm->Gd[tid] = P.gd[tid]; sm->Bed[tid] = P.bed[tid]; }
  if (tid < VOC) sm->Bh[tid] = P.bh[tid];
  if (tid < DI) sm->Bb[tid] = P.bb[tid];
  if (tid >= 64 && tid < 96) {           // PC tables (j = tid-64)
    int j = tid - 64;
    float pc1 = 0.f, pc2 = 0.f;
    for (int k = 0; k < 256; ++k) {
      float w = P.Wd[k * 32 + j];
      pc1 += P.bef[k] * w;
      pc2 += P.gf[k] * w;
    }
    sm->PC1[j] = pc1; sm->PC2[j] = pc2;
  }
  for (int i = tid; i < MEMN * DM; i += 512) {
    int mm = i >> 8, d = i & 255;
    sm->St[mm * DM + d] = P.st0[d * MEMN + mm];
  }
  if (tid < DI) sm->X2[0][tid] = P.x[(size_t)b * T_LEN * DI + tid];
  for (int i = tid; i < SYNCD * VOC; i += 512) sm->WhL[i] = P.Wh[i];
  for (int pp = tid; pp < SYNCD; pp += 512) {
    int i = 0, cum = 0;
    while (pp >= cum + (32 - i)) { cum += 32 - i; ++i; }
    sm->Pair[pp] = (i << 8) | (i + (pp - cum));
  }
  // initial act pack (permuted layout): word 32+mc+64b = (act[mc+128b], act[mc+64+128b])
  if (tid < 128) {
    int mc = tid & 63, bb_ = tid >> 6;
    float a0 = P.ast0[(mc + 128 * bb_) * MEMN + (MEMN - 1)];
    float a1 = P.ast0[(mc + 64 + 128 * bb_) * MEMN + (MEMN - 1)];
    sm->Pre2[32 + mc + 64 * bb_] = pack2(a0, a1);
  }

  // ---------------- register weights ----------------
  const int o = tid & 7;                 // K-eighth (chunks [5o,5o+5))
  const int mc = tid >> 3;               // column base 0..63; cols owned: mc+64K
  const int ch = mc + 64 * ((tid >> 1) & 3);   // this lane's output channel
  const f16x8* wf8 = (const f16x8*)P.wf16;
  FOR8K(DECLW)
  FOR8K(LOADW)
  const int jD = tid & 31, kcD = tid >> 5;   // Wd partial mapping
  float wd[16];
  #pragma unroll
  for (int q = 0; q < 16; ++q) wd[q] = P.Wd[(kcD * 16 + q) * 32 + jD];
  const int p = tid & 1;                 // Wu K-half (pair lanes share ch)
  float wua[8], wub[8];
  #pragma unroll
  for (int q = 0; q < 8; ++q) {
    wua[q] = P.Wu[(p * 8 + q) * 512 + ch];
    wub[q] = P.Wu[(p * 8 + q) * 512 + ch + 256];
  }
  const int jK = tid & 63, kcK = tid >> 6;   // Wb mapping
  float wbr[8];
  #pragma unroll
  for (int q = 0; q < 8; ++q) wbr[q] = P.Wb[(kcK * 8 + q) * 64 + jK];

  __syncthreads();

  // ---------------- prologue: kv(t=0) ----------------
  {
    float s = 0.f;
    #pragma unroll
    for (int q = 0; q < 8; ++q) s += sm->X2[0][kcK * 8 + q] * wbr[q];
    sm->PartK[kcK * 64 + jK] = s;
  }
  __syncthreads();
  if (tid >= 256 && tid < 320) {
    int j = tid - 256;
    float kv = sm->Bb[j];
    #pragma unroll
    for (int kc = 0; kc < 8; ++kc) kv += sm->PartK[kc * 64 + j];
    kv = fmaxf(kv, 0.f);
    float kn = DPP_TERM(kv, 0xB1, 0xF);
    if ((j & 1) == 0) sm->Pre2[j >> 1] = pack2(kv, kn);
  }
  __syncthreads();

  int head = 0;
  for (int t = 0; t < T_LEN; ++t) {
    float xr = 0.f;

    for (int it = 0; it < 2; ++it) {
      // ---- P1: Wf GEMV (8 cols x 1/8-K) + octet reduce + GLU + LN-reduce ----
      if (it == 1 && tid < DI) sm->X2[(t + 1) & 1][tid] = xr;
      float ac0 = 0.f, ac1 = 0.f, ac2 = 0.f, ac3 = 0.f;
      float ac4 = 0.f, ac5 = 0.f, ac6 = 0.f, ac7 = 0.f;
      const f16x8* pr8 = (const f16x8*)sm->Pre2;
      DOTJ(0) DOTJ(1) DOTJ(2) DOTJ(3) DOTJ(4)
      OSUM(ac0); OSUM(ac1); OSUM(ac2); OSUM(ac3);
      OSUM(ac4); OSUM(ac5); OSUM(ac6); OSUM(ac7);
      float aa = (tid & 4) ? ((tid & 2) ? ac3 : ac2) : ((tid & 2) ? ac1 : ac0);
      float bb_ = (tid & 4) ? ((tid & 2) ? ac7 : ac6) : ((tid & 2) ? ac5 : ac4);
      aa += sm->Bf[ch]; bb_ += sm->Bf[DM + ch];
      float g = aa * sigm(bb_);
      float gf_c = sm->Gf[ch];
      float ghat = g * gf_c;
      if ((tid & 1) == 0) sm->G[ch] = ghat;
      float s1 = g, s2 = g * g;
      WSUM2(s1, s2);
      if ((tid & 63) == 63) { float2 r; r.x = s1; r.y = s2; sm->RedAB[tid >> 6] = r; }
      __syncthreads();  // B1

      // ---- P2: Wd partials from Ghat (LN folded out); h0v in-reg; x prefetch ----
      if (it == 0 && tid < DI && t + 1 < T_LEN)
        xr = P.x[((size_t)b * T_LEN + (t + 1)) * DI + tid];
      float S1 = 0.f, S2 = 0.f;
      #pragma unroll
      for (int w = 0; w < 8; ++w) { float2 r = sm->RedAB[w]; S1 += r.x; S2 += r.y; }
      float mean_f = S1 * (1.0f / 512.0f);
      float var_f = S2 * (1.0f / 512.0f) - mean_f * mean_f;
      float r_f = rsqrtf(var_f + 1e-5f);
      float h0v = (g - mean_f) * r_f * gf_c + sm->Bef[ch];
      {
        float s = 0.f;
        #pragma unroll
        for (int qq = 0; qq < 4; ++qq) {
          float4 hv = ((const float4*)sm->G)[kcD * 4 + qq];
          s += hv.x * wd[qq * 4 + 0] + hv.y * wd[qq * 4 + 1]
             + hv.z * wd[qq * 4 + 2] + hv.w * wd[qq * 4 + 3];
        }
        sm->PartD[kcD * 33 + jD] = s;
      }
      __syncthreads();  // B2

      // ---- P3: d1 = LN(GLU(Wd out)) with LN-fold assembly (lanes 0-31) ----
      if (tid < 32) {
        float S = 0.f;
        #pragma unroll
        for (int kc = 0; kc < 16; ++kc) S += sm->PartD[kc * 33 + tid];
        float raw = r_f * S - mean_f * r_f * sm->PC2[tid] + sm->PC1[tid] + sm->Bd[tid];
        float oth = __shfl_xor(raw, 16);
        float gg = raw * sigm(oth);     // valid on lanes 0-15
        float t1 = gg, t2 = gg * gg;
        DPPADD(t1, 0x111, 0xF); DPPADD(t2, 0x111, 0xF);
        DPPADD(t1, 0x112, 0xF); DPPADD(t2, 0x112, 0xF);
        DPPADD(t1, 0x114, 0xF); DPPADD(t2, 0x114, 0xF);
        DPPADD(t1, 0x118, 0xF); DPPADD(t2, 0x118, 0xF);
        float T1 = readlane_f(t1, 15), T2 = readlane_f(t2, 15);
        float mn = T1 * (1.0f / 16.0f), vr = T2 * (1.0f / 16.0f) - mn * mn;
        float d1 = (gg - mn) * rsqrtf(vr + 1e-5f) * sm->Gd[tid & 15] + sm->Bed[tid & 15];
        if (tid < 16) sm->D1[tid] = d1;
      }
      __syncthreads();  // B3

      // ---- P4: Wu (K-half by pair parity) + GLU + wave-reduce ----
      float gu;
      {
        const float4* d4 = (const float4*)sm->D1;
        float4 dl = d4[p * 2], dh = d4[p * 2 + 1];
        float ua = dl.x * wua[0] + dl.y * wua[1] + dl.z * wua[2] + dl.w * wua[3]
                 + dh.x * wua[4] + dh.y * wua[5] + dh.z * wua[6] + dh.w * wua[7];
        float ub = dl.x * wub[0] + dl.y * wub[1] + dl.z * wub[2] + dl.w * wub[3]
                 + dh.x * wub[4] + dh.y * wub[5] + dh.z * wub[6] + dh.w * wub[7];
        DPPADD(ua, 0xB1, 0xF);
        DPPADD(ub, 0xB1, 0xF);
        ua += sm->Bu[ch]; ub += sm->Bu[DM + ch];
        gu = ua * sigm(ub);
        float t1 = gu, t2 = gu * gu;
        WSUM2(t1, t2);
        if ((tid & 63) == 63) { float2 r; r.x = t1; r.y = t2; sm->RedAB[tid >> 6] = r; }
      }
      __syncthreads();  // B4

      // ---- P5: u0 = LN(gu); x2 = u0 + h0v; reduce for state-LN ----
      float x2v;
      {
        float U1 = 0.f, U2 = 0.f;
        #pragma unroll
        for (int w = 0; w < 8; ++w) { float2 r = sm->RedAB[w]; U1 += r.x; U2 += r.y; }
        float mn = U1 * (1.0f / 512.0f), vr = U2 * (1.0f / 512.0f) - mn * mn;
        float u0 = (gu - mn) * rsqrtf(vr + 1e-5f) * sm->Gu[ch] + sm->Beu[ch];
        x2v = u0 + h0v;
        float t1 = x2v, t2 = x2v * x2v;
        WSUM2(t1, t2);
        if ((tid & 63) == 63) { float2 r; r.x = t1; r.y = t2; sm->Red2AB[tid >> 6] = r; }
      }
      __syncthreads();  // B5

      // ---- P6: state = LN(x2); trace; nlm -> act; permuted Pre2 act write ----
      {
        float V1 = 0.f, V2 = 0.f;
        #pragma unroll
        for (int w = 0; w < 8; ++w) { float2 r = sm->Red2AB[w]; V1 += r.x; V2 += r.y; }
        float mn = V1 * (1.0f / 512.0f), vr = V2 * (1.0f / 512.0f) - mn * mn;
        float state = (x2v - mn) * rsqrtf(vr + 1e-5f) * sm->Gs[ch] + sm->Bes[ch];
        if ((tid & 1) == 0) sm->St[head * DM + ch] = state;
        float4 h1 = sm->B1v[ch];
        int base = head + 1; if (base >= MEMN) base -= MEMN;
        #pragma unroll
        for (int mm = 0; mm < MEMN - 1; ++mm) {
          int slot = base + mm; if (slot >= MEMN) slot -= MEMN;
          float tr = sm->St[slot * DM + ch];
          float4 wv = sm->W1v[mm * DM + ch];
          h1.x += tr * wv.x; h1.y += tr * wv.y; h1.z += tr * wv.z; h1.w += tr * wv.w;
        }
        {
          float4 wv = sm->W1v[(MEMN - 1) * DM + ch];
          h1.x += state * wv.x; h1.y += state * wv.y; h1.z += state * wv.z; h1.w += state * wv.w;
        }
        float g0 = h1.x * sigm(h1.z), g1 = h1.y * sigm(h1.w);
        float4 w2v = sm->W2v[ch];
        float2 b2v = sm->B2v[ch];
        float o0 = g0 * w2v.x + g1 * w2v.z + b2v.x;
        float o1 = g0 * w2v.y + g1 * w2v.w + b2v.y;
        float act = o0 * sigm(o1);
        if ((tid & 1) == 0) sm->Act[ch] = act;
        // partner act via quad_perm [2,3,0,1]: lane o=0 <- o=2 (ch mc+64), o=4 <- o=6 (mc+192)
        float apart = DPP_TERM(act, 0x4E, 0xF);
        if (o == 0) sm->Pre2[32 + mc] = pack2(act, apart);
        if (o == 4) sm->Pre2[32 + 64 + mc] = pack2(act, apart);
        head += 1; if (head >= MEMN) head = 0;
      }
      __syncthreads();  // B6
    }  // it

    // ---- S1: sync products + next-step Wb partials + store logits(t-1) ----
    {
      int pr = sm->Pair[tid];
      sm->Prod[tid] = sm->Act[pr >> 8] * sm->Act[pr & 255];
      if (tid < SYNCD - 512) {
        int pr2 = sm->Pair[512 + tid];
        sm->Prod[512 + tid] = sm->Act[pr2 >> 8] * sm->Act[pr2 & 255];
      }
      const float* X = sm->X2[(t + 1) & 1];
      float s = 0.f;
      #pragma unroll
      for (int q = 0; q < 8; ++q) s += X[kcK * 8 + q] * wbr[q];
      sm->PartK[kcK * 64 + jK] = s;
      if (t > 0 && tid < VOC) {
        float o_ = sm->Bh[tid];
        #pragma unroll
        for (int kc2 = 0; kc2 < 16; ++kc2) o_ += sm->PartH[kc2 * 15 + tid];
        P.out[((size_t)b * T_LEN + (t - 1)) * VOC + tid] = o_;
      }
    }
    __syncthreads();  // B7

    // ---- S2: Wh partials + kv reduce/pack for t+1 ----
    if (tid < 240) {
      int kc = (tid * 4370) >> 16;
      int v = tid - kc * 15;
      float s = 0.f;
      #pragma unroll
      for (int q = 0; q < 33; ++q) {
        int pp = kc * 33 + q;
        s += sm->Prod[pp] * sm->WhL[pp * 15 + v];
      }
      sm->PartH[kc * 15 + v] = s;
    } else if (tid >= 256 && tid < 320) {
      int j = tid - 256;
      float kv = sm->Bb[j];
      #pragma unroll
      for (int kc = 0; kc < 8; ++kc) kv += sm->PartK[kc * 64 + j];
      kv = fmaxf(kv, 0.f);
      float kn = DPP_TERM(kv, 0xB1, 0xF);
      if ((j & 1) == 0) sm->Pre2[j >> 1] = pack2(kv, kn);
    }
    __syncthreads();  // B8
  }  // t

  if (tid < VOC) {
    float o_ = sm->Bh[tid];
    #pragma unroll
    for (int kc = 0; kc < 16; ++kc) o_ += sm->PartH[kc * 15 + tid];
    P.out[((size_t)b * T_LEN + (T_LEN - 1)) * VOC + tid] = o_;
  }
}

extern "C" void kernel_launch(void* const* d_in, const int* in_sizes, int n_in,
                              void* d_out, int out_size, void* d_ws, size_t ws_size,
                              hipStream_t stream) {
  (void)n_in; (void)out_size; (void)ws_size;
  Params P;
  P.x   = (const float*)d_in[0];
  P.st0 = (const float*)d_in[1];
  P.ast0= (const float*)d_in[2];
  P.Wb  = (const float*)d_in[3];
  P.bb  = (const float*)d_in[4];
  P.Wf  = (const float*)d_in[5];
  P.bf  = (const float*)d_in[6];
  P.gf  = (const float*)d_in[7];
  P.bef = (const float*)d_in[8];
  P.Wd  = (const float*)d_in[9];
  P.bd  = (const float*)d_in[10];
  P.gd  = (const float*)d_in[11];
  P.bed = (const float*)d_in[12];
  P.Wu  = (const float*)d_in[13];
  P.bu  = (const float*)d_in[14];
  P.gu  = (const float*)d_in[15];
  P.beu = (const float*)d_in[16];
  P.gs  = (const float*)d_in[17];
  P.bes = (const float*)d_in[18];
  P.w1  = (const float*)d_in[19];
  P.b1  = (const float*)d_in[20];
  P.w2  = (const float*)d_in[21];
  P.b2  = (const float*)d_in[22];
  P.Wh  = (const float*)d_in[23];
  P.bh  = (const float*)d_in[24];
  P.out = (float*)d_out;

  f16* wf16 = (f16*)d_ws;
  hipLaunchKernelGGL(wf16_kernel, dim3(320), dim3(512), 0, stream, P.Wf, wf16);
  P.wf16 = wf16;

  int B = in_sizes[0] / (T_LEN * DI);
  hipLaunchKernelGGL(ctm_kernel, dim3(B), dim3(512), 0, stream, P);
}

// Round 11
// 13361.519 us; speedup vs baseline: 1.0501x; 1.0501x over previous
//
#include <hip/hip_runtime.h>
#include <math.h>

#define T_LEN 1500
#define DM 256
#define DI 64
#define MEMN 10
#define SYNCD 528
#define VOC 15

typedef _Float16 f16;
typedef _Float16 f16x2 __attribute__((ext_vector_type(2)));
typedef _Float16 f16x8 __attribute__((ext_vector_type(8)));

#define FDOT2(a, b, c) __builtin_amdgcn_fdot2((a), (b), (c), false)

static __device__ __forceinline__ float dot8(f16x8 w, f16x8 q, float acc) {
  acc = FDOT2(__builtin_shufflevector(w, w, 0, 1), __builtin_shufflevector(q, q, 0, 1), acc);
  acc = FDOT2(__builtin_shufflevector(w, w, 2, 3), __builtin_shufflevector(q, q, 2, 3), acc);
  acc = FDOT2(__builtin_shufflevector(w, w, 4, 5), __builtin_shufflevector(q, q, 4, 5), acc);
  acc = FDOT2(__builtin_shufflevector(w, w, 6, 7), __builtin_shufflevector(q, q, 6, 7), acc);
  return acc;
}
static __device__ __forceinline__ f16x2 pack2(float a, float b) {
  f16x2 r; r.x = (_Float16)a; r.y = (_Float16)b; return r;
}
static __device__ __forceinline__ float sigm(float x) { return 1.0f / (1.0f + __expf(-x)); }

// ---- DPP cross-lane ----
#define DPP_TERM(x, ctrl, rmask) \
  __int_as_float(__builtin_amdgcn_update_dpp(0, __float_as_int(x), (ctrl), (rmask), 0xF, true))
#define DPPADD(x, ctrl, rmask) (x) += DPP_TERM(x, ctrl, rmask)
// full 64-lane sum of a and b; valid in lane 63
#define WSUM2(a, b) do { \
  DPPADD(a, 0x111, 0xF); DPPADD(b, 0x111, 0xF); \
  DPPADD(a, 0x112, 0xF); DPPADD(b, 0x112, 0xF); \
  DPPADD(a, 0x114, 0xF); DPPADD(b, 0x114, 0xF); \
  DPPADD(a, 0x118, 0xF); DPPADD(b, 0x118, 0xF); \
  DPPADD(a, 0x142, 0xA); DPPADD(b, 0x142, 0xA); \
  DPPADD(a, 0x143, 0xC); DPPADD(b, 0x143, 0xC); \
} while (0)
// octet (8-lane) total into all 8 lanes: xor1, xor2 (quad_perm), then half-mirror cross-quad
#define OSUM(x) do { DPPADD(x, 0xB1, 0xF); DPPADD(x, 0x4E, 0xF); DPPADD(x, 0x141, 0xF); } while (0)
static __device__ __forceinline__ float readlane_f(float x, int l) {
  return __int_as_float(__builtin_amdgcn_readlane(__float_as_int(x), l));
}

struct Params {
  const float *x, *st0, *ast0, *Wb, *bb, *Wf, *bf, *gf, *bef,
              *Wd, *bd, *gd, *bed, *Wu, *bu, *gu, *beu, *gs, *bes,
              *w1, *b1, *w2, *b2, *Wh, *bh;
  const f16* wf16;
  float* out;
};

struct Smem {
  float4 W1v[MEMN * DM];
  float4 W2v[DM];
  float4 B1v[DM];
  float2 B2v[DM];
  float Bf[2 * DM];
  float Bu[2 * DM];
  float Bd[32];
  float Gf[DM], Bef[DM], Gu[DM], Beu[DM], Gs[DM], Bes[DM];
  float Gd[16], Bed[16];
  float Bh[16];
  float Bb[DI];
  float PC1[32], PC2[32];       // LN-fold tables: sum_k Bef_k*Wd[k][j], sum_k Gf_k*Wd[k][j]
  __attribute__((aligned(16))) float St[MEMN * DM];
  __attribute__((aligned(16))) float G[DM];           // ghat = g*Gf
  float Act[DM];
  __attribute__((aligned(16))) float D1[16];
  float X2[2][DI];
  __attribute__((aligned(16))) f16x2 Pre2[160];       // [0..31]=kv pairs, [32..159]=(act[2j],act[2j+1])
  float PartD[16 * 33];
  float PartK[512];
  float PartH[240];
  float2 RedAB[8];
  float2 Red2AB[8];
  float Prod[SYNCD];
  float WhL[SYNCD * VOC];
  int Pair[SYNCD];
};

// Wf f32 [k][col] -> f16 chunk-major [k/8][col][k%8] (natural K order).
__global__ __launch_bounds__(512) void wf16_kernel(const float* __restrict__ Wf,
                                                   f16* __restrict__ out) {
  int k = blockIdx.x;          // 0..319
  int c = threadIdx.x;         // 0..511
  out[((size_t)(k >> 3) * 512 + (size_t)c) * 8 + (k & 7)] = (f16)Wf[(size_t)k * 512 + c];
}

#define FOR8K(X) X(0) X(1) X(2) X(3) X(4) X(5) X(6) X(7)
#define DECLW(K) f16x8 w##K##_0, w##K##_1, w##K##_2, w##K##_3, w##K##_4;
// octet mc owns a-cols {4mc..4mc+3} (K=0..3) and b-cols {4mc+256..} (K=4..7)
#define LOADW(K) { size_t cb = (size_t)(4 * mc + ((K) < 4 ? (K) : (K) - 4 + 256)); \
  w##K##_0 = wf8[(size_t)(5 * o + 0) * 512 + cb]; \
  w##K##_1 = wf8[(size_t)(5 * o + 1) * 512 + cb]; \
  w##K##_2 = wf8[(size_t)(5 * o + 2) * 512 + cb]; \
  w##K##_3 = wf8[(size_t)(5 * o + 3) * 512 + cb]; \
  w##K##_4 = wf8[(size_t)(5 * o + 4) * 512 + cb]; }
#define DOTJ(J) { f16x8 q_ = pr8[5 * o + (J)]; \
  ac0 = dot8(w0_##J, q_, ac0); ac1 = dot8(w1_##J, q_, ac1); \
  ac2 = dot8(w2_##J, q_, ac2); ac3 = dot8(w3_##J, q_, ac3); \
  ac4 = dot8(w4_##J, q_, ac4); ac5 = dot8(w5_##J, q_, ac5); \
  ac6 = dot8(w6_##J, q_, ac6); ac7 = dot8(w7_##J, q_, ac7); }

__global__ __launch_bounds__(512) __attribute__((amdgpu_waves_per_eu(2, 2)))
void ctm_kernel(Params P) {
  const int tid = threadIdx.x;
  const int b = blockIdx.x;
  __shared__ Smem sm_s;
  Smem* sm = &sm_s;

  // ---------------- LDS preload (once) ----------------
  for (int i = tid; i < MEMN * DM; i += 512) sm->W1v[i] = ((const float4*)P.w1)[i];
  if (tid < DM) {
    float2 a = ((const float2*)P.w2)[tid];
    float2 c = ((const float2*)P.w2)[DM + tid];
    float4 w; w.x = a.x; w.y = a.y; w.z = c.x; w.w = c.y;
    sm->W2v[tid] = w;
    sm->B1v[tid] = ((const float4*)P.b1)[tid];
    sm->B2v[tid] = ((const float2*)P.b2)[tid];
    sm->Gf[tid] = P.gf[tid]; sm->Bef[tid] = P.bef[tid];
    sm->Gu[tid] = P.gu[tid]; sm->Beu[tid] = P.beu[tid];
    sm->Gs[tid] = P.gs[tid]; sm->Bes[tid] = P.bes[tid];
  }
  sm->Bf[tid] = P.bf[tid];
  sm->Bu[tid] = P.bu[tid];
  if (tid < 32) sm->Bd[tid] = P.bd[tid];
  if (tid < 16) { sm->Gd[tid] = P.gd[tid]; sm->Bed[tid] = P.bed[tid]; }
  if (tid < VOC) sm->Bh[tid] = P.bh[tid];
  if (tid < DI) sm->Bb[tid] = P.bb[tid];
  if (tid >= 64 && tid < 96) {           // PC tables (j = tid-64)
    int j = tid - 64;
    float pc1 = 0.f, pc2 = 0.f;
    for (int k = 0; k < 256; ++k) {
      float w = P.Wd[k * 32 + j];
      pc1 += P.bef[k] * w;
      pc2 += P.gf[k] * w;
    }
    sm->PC1[j] = pc1; sm->PC2[j] = pc2;
  }
  for (int i = tid; i < MEMN * DM; i += 512) {
    int mm = i >> 8, d = i & 255;
    sm->St[mm * DM + d] = P.st0[d * MEMN + mm];
  }
  if (tid < DI) sm->X2[0][tid] = P.x[(size_t)b * T_LEN * DI + tid];
  for (int i = tid; i < SYNCD * VOC; i += 512) sm->WhL[i] = P.Wh[i];
  for (int pp = tid; pp < SYNCD; pp += 512) {
    int i = 0, cum = 0;
    while (pp >= cum + (32 - i)) { cum += 32 - i; ++i; }
    sm->Pair[pp] = (i << 8) | (i + (pp - cum));
  }
  // initial act pack (natural order): word 32+j = (act[2j], act[2j+1])
  if (tid < 128) {
    float a0 = P.ast0[(2 * tid) * MEMN + (MEMN - 1)];
    float a1 = P.ast0[(2 * tid + 1) * MEMN + (MEMN - 1)];
    sm->Pre2[32 + tid] = pack2(a0, a1);
  }

  // ---------------- register weights ----------------
  const int o = tid & 7;                 // K-eighth (chunks [5o,5o+5))
  const int mc = tid >> 3;               // octet id 0..63; owns cols 4mc..4mc+3 (+256)
  const int ch = tid >> 1;               // this lane's output channel (conflict-free map)
  const f16x8* wf8 = (const f16x8*)P.wf16;
  FOR8K(DECLW)
  FOR8K(LOADW)
  const int jD = tid & 31, kcD = tid >> 5;   // Wd partial mapping
  float wd[16];
  #pragma unroll
  for (int q = 0; q < 16; ++q) wd[q] = P.Wd[(kcD * 16 + q) * 32 + jD];
  const int p = tid & 1;                 // Wu K-half (pair lanes share ch)
  float wua[8], wub[8];
  #pragma unroll
  for (int q = 0; q < 8; ++q) {
    wua[q] = P.Wu[(p * 8 + q) * 512 + ch];
    wub[q] = P.Wu[(p * 8 + q) * 512 + ch + 256];
  }
  const int jK = tid & 63, kcK = tid >> 6;   // Wb mapping
  float wbr[8];
  #pragma unroll
  for (int q = 0; q < 8; ++q) wbr[q] = P.Wb[(kcK * 8 + q) * 64 + jK];

  __syncthreads();

  // ---------------- prologue: kv(t=0) ----------------
  {
    float s = 0.f;
    #pragma unroll
    for (int q = 0; q < 8; ++q) s += sm->X2[0][kcK * 8 + q] * wbr[q];
    sm->PartK[kcK * 64 + jK] = s;
  }
  __syncthreads();
  if (tid >= 256 && tid < 320) {
    int j = tid - 256;
    float kv = sm->Bb[j];
    #pragma unroll
    for (int kc = 0; kc < 8; ++kc) kv += sm->PartK[kc * 64 + j];
    kv = fmaxf(kv, 0.f);
    float kn = DPP_TERM(kv, 0xB1, 0xF);
    if ((j & 1) == 0) sm->Pre2[j >> 1] = pack2(kv, kn);
  }
  __syncthreads();

  int head = 0;
  for (int t = 0; t < T_LEN; ++t) {
    float xr = 0.f;

    for (int it = 0; it < 2; ++it) {
      // ---- P1: Wf GEMV (8 consecutive cols x 1/8-K) + octet reduce + GLU + LN-reduce ----
      if (it == 1 && tid < DI) sm->X2[(t + 1) & 1][tid] = xr;
      float ac0 = 0.f, ac1 = 0.f, ac2 = 0.f, ac3 = 0.f;
      float ac4 = 0.f, ac5 = 0.f, ac6 = 0.f, ac7 = 0.f;
      const f16x8* pr8 = (const f16x8*)sm->Pre2;
      DOTJ(0) DOTJ(1) DOTJ(2) DOTJ(3) DOTJ(4)
      OSUM(ac0); OSUM(ac1); OSUM(ac2); OSUM(ac3);
      OSUM(ac4); OSUM(ac5); OSUM(ac6); OSUM(ac7);
      float aa = (tid & 4) ? ((tid & 2) ? ac3 : ac2) : ((tid & 2) ? ac1 : ac0);
      float bb_ = (tid & 4) ? ((tid & 2) ? ac7 : ac6) : ((tid & 2) ? ac5 : ac4);
      aa += sm->Bf[ch]; bb_ += sm->Bf[DM + ch];
      float g = aa * sigm(bb_);
      float gf_c = sm->Gf[ch];
      float ghat = g * gf_c;
      if ((tid & 1) == 0) sm->G[ch] = ghat;
      float s1 = g, s2 = g * g;
      WSUM2(s1, s2);
      if ((tid & 63) == 63) { float2 r; r.x = s1; r.y = s2; sm->RedAB[tid >> 6] = r; }
      __syncthreads();  // B1

      // ---- P2: Wd partials from Ghat (LN folded); h0v in-reg; x prefetch ----
      if (it == 0 && tid < DI && t + 1 < T_LEN)
        xr = P.x[((size_t)b * T_LEN + (t + 1)) * DI + tid];
      float S1 = 0.f, S2 = 0.f;
      #pragma unroll
      for (int w = 0; w < 8; ++w) { float2 r = sm->RedAB[w]; S1 += r.x; S2 += r.y; }
      float mean_f = S1 * (1.0f / 512.0f);
      float var_f = S2 * (1.0f / 512.0f) - mean_f * mean_f;
      float r_f = rsqrtf(var_f + 1e-5f);
      float h0v = (g - mean_f) * r_f * gf_c + sm->Bef[ch];
      {
        float s = 0.f;
        #pragma unroll
        for (int qq = 0; qq < 4; ++qq) {
          float4 hv = ((const float4*)sm->G)[kcD * 4 + qq];
          s += hv.x * wd[qq * 4 + 0] + hv.y * wd[qq * 4 + 1]
             + hv.z * wd[qq * 4 + 2] + hv.w * wd[qq * 4 + 3];
        }
        sm->PartD[kcD * 33 + jD] = s;
      }
      __syncthreads();  // B2

      // ---- P3: d1 = LN(GLU(Wd out)) with LN-fold assembly (lanes 0-31) ----
      if (tid < 32) {
        float S = 0.f;
        #pragma unroll
        for (int kc = 0; kc < 16; ++kc) S += sm->PartD[kc * 33 + tid];
        float raw = r_f * S - mean_f * r_f * sm->PC2[tid] + sm->PC1[tid] + sm->Bd[tid];
        float oth = __shfl_xor(raw, 16);
        float gg = raw * sigm(oth);     // valid on lanes 0-15
        float t1 = gg, t2 = gg * gg;
        DPPADD(t1, 0x111, 0xF); DPPADD(t2, 0x111, 0xF);
        DPPADD(t1, 0x112, 0xF); DPPADD(t2, 0x112, 0xF);
        DPPADD(t1, 0x114, 0xF); DPPADD(t2, 0x114, 0xF);
        DPPADD(t1, 0x118, 0xF); DPPADD(t2, 0x118, 0xF);
        float T1 = readlane_f(t1, 15), T2 = readlane_f(t2, 15);
        float mn = T1 * (1.0f / 16.0f), vr = T2 * (1.0f / 16.0f) - mn * mn;
        float d1 = (gg - mn) * rsqrtf(vr + 1e-5f) * sm->Gd[tid & 15] + sm->Bed[tid & 15];
        if (tid < 16) sm->D1[tid] = d1;
      }
      __syncthreads();  // B3

      // ---- P4: Wu (K-half by pair parity) + GLU + wave-reduce ----
      float gu;
      {
        const float4* d4 = (const float4*)sm->D1;
        float4 dl = d4[p * 2], dh = d4[p * 2 + 1];
        float ua = dl.x * wua[0] + dl.y * wua[1] + dl.z * wua[2] + dl.w * wua[3]
                 + dh.x * wua[4] + dh.y * wua[5] + dh.z * wua[6] + dh.w * wua[7];
        float ub = dl.x * wub[0] + dl.y * wub[1] + dl.z * wub[2] + dl.w * wub[3]
                 + dh.x * wub[4] + dh.y * wub[5] + dh.z * wub[6] + dh.w * wub[7];
        DPPADD(ua, 0xB1, 0xF);
        DPPADD(ub, 0xB1, 0xF);
        ua += sm->Bu[ch]; ub += sm->Bu[DM + ch];
        gu = ua * sigm(ub);
        float t1 = gu, t2 = gu * gu;
        WSUM2(t1, t2);
        if ((tid & 63) == 63) { float2 r; r.x = t1; r.y = t2; sm->RedAB[tid >> 6] = r; }
      }
      __syncthreads();  // B4

      // ---- P5: u0 = LN(gu); x2 = u0 + h0v; reduce for state-LN ----
      float x2v;
      {
        float U1 = 0.f, U2 = 0.f;
        #pragma unroll
        for (int w = 0; w < 8; ++w) { float2 r = sm->RedAB[w]; U1 += r.x; U2 += r.y; }
        float mn = U1 * (1.0f / 512.0f), vr = U2 * (1.0f / 512.0f) - mn * mn;
        float u0 = (gu - mn) * rsqrtf(vr + 1e-5f) * sm->Gu[ch] + sm->Beu[ch];
        x2v = u0 + h0v;
        float t1 = x2v, t2 = x2v * x2v;
        WSUM2(t1, t2);
        if ((tid & 63) == 63) { float2 r; r.x = t1; r.y = t2; sm->Red2AB[tid >> 6] = r; }
      }
      __syncthreads();  // B5

      // ---- P6: state = LN(x2); trace; nlm -> act; natural Pre2 act write ----
      {
        float V1 = 0.f, V2 = 0.f;
        #pragma unroll
        for (int w = 0; w < 8; ++w) { float2 r = sm->Red2AB[w]; V1 += r.x; V2 += r.y; }
        float mn = V1 * (1.0f / 512.0f), vr = V2 * (1.0f / 512.0f) - mn * mn;
        float state = (x2v - mn) * rsqrtf(vr + 1e-5f) * sm->Gs[ch] + sm->Bes[ch];
        if ((tid & 1) == 0) sm->St[head * DM + ch] = state;
        float4 h1 = sm->B1v[ch];
        int base = head + 1; if (base >= MEMN) base -= MEMN;
        #pragma unroll
        for (int mm = 0; mm < MEMN - 1; ++mm) {
          int slot = base + mm; if (slot >= MEMN) slot -= MEMN;
          float tr = sm->St[slot * DM + ch];
          float4 wv = sm->W1v[mm * DM + ch];
          h1.x += tr * wv.x; h1.y += tr * wv.y; h1.z += tr * wv.z; h1.w += tr * wv.w;
        }
        {
          float4 wv = sm->W1v[(MEMN - 1) * DM + ch];
          h1.x += state * wv.x; h1.y += state * wv.y; h1.z += state * wv.z; h1.w += state * wv.w;
        }
        float g0 = h1.x * sigm(h1.z), g1 = h1.y * sigm(h1.w);
        float4 w2v = sm->W2v[ch];
        float2 b2v = sm->B2v[ch];
        float o0 = g0 * w2v.x + g1 * w2v.z + b2v.x;
        float o1 = g0 * w2v.y + g1 * w2v.w + b2v.y;
        float act = o0 * sigm(o1);
        if ((tid & 1) == 0) sm->Act[ch] = act;
        // partner act via quad_perm [2,3,0,1]: lane o=0 <- o=2 (ch+1); o=4 <- o=6 (ch+1)
        float apart = DPP_TERM(act, 0x4E, 0xF);
        if (o == 0) sm->Pre2[32 + 2 * mc] = pack2(act, apart);        // (act[4mc], act[4mc+1])
        if (o == 4) sm->Pre2[32 + 2 * mc + 1] = pack2(act, apart);    // (act[4mc+2], act[4mc+3])
        head += 1; if (head >= MEMN) head = 0;
      }
      __syncthreads();  // B6
    }  // it

    // ---- S1: sync products + next-step Wb partials + store logits(t-1) ----
    {
      int pr = sm->Pair[tid];
      sm->Prod[tid] = sm->Act[pr >> 8] * sm->Act[pr & 255];
      if (tid < SYNCD - 512) {
        int pr2 = sm->Pair[512 + tid];
        sm->Prod[512 + tid] = sm->Act[pr2 >> 8] * sm->Act[pr2 & 255];
      }
      const float* X = sm->X2[(t + 1) & 1];
      float s = 0.f;
      #pragma unroll
      for (int q = 0; q < 8; ++q) s += X[kcK * 8 + q] * wbr[q];
      sm->PartK[kcK * 64 + jK] = s;
      if (t > 0 && tid < VOC) {
        float o_ = sm->Bh[tid];
        #pragma unroll
        for (int kc2 = 0; kc2 < 16; ++kc2) o_ += sm->PartH[kc2 * 15 + tid];
        P.out[((size_t)b * T_LEN + (t - 1)) * VOC + tid] = o_;
      }
    }
    __syncthreads();  // B7

    // ---- S2: Wh partials + kv reduce/pack for t+1 ----
    if (tid < 240) {
      int kc = (tid * 4370) >> 16;
      int v = tid - kc * 15;
      float s = 0.f;
      #pragma unroll
      for (int q = 0; q < 33; ++q) {
        int pp = kc * 33 + q;
        s += sm->Prod[pp] * sm->WhL[pp * 15 + v];
      }
      sm->PartH[kc * 15 + v] = s;
    } else if (tid >= 256 && tid < 320) {
      int j = tid - 256;
      float kv = sm->Bb[j];
      #pragma unroll
      for (int kc = 0; kc < 8; ++kc) kv += sm->PartK[kc * 64 + j];
      kv = fmaxf(kv, 0.f);
      float kn = DPP_TERM(kv, 0xB1, 0xF);
      if ((j & 1) == 0) sm->Pre2[j >> 1] = pack2(kv, kn);
    }
    __syncthreads();  // B8
  }  // t

  if (tid < VOC) {
    float o_ = sm->Bh[tid];
    #pragma unroll
    for (int kc = 0; kc < 16; ++kc) o_ += sm->PartH[kc * 15 + tid];
    P.out[((size_t)b * T_LEN + (T_LEN - 1)) * VOC + tid] = o_;
  }
}

extern "C" void kernel_launch(void* const* d_in, const int* in_sizes, int n_in,
                              void* d_out, int out_size, void* d_ws, size_t ws_size,
                              hipStream_t stream) {
  (void)n_in; (void)out_size; (void)ws_size;
  Params P;
  P.x   = (const float*)d_in[0];
  P.st0 = (const float*)d_in[1];
  P.ast0= (const float*)d_in[2];
  P.Wb  = (const float*)d_in[3];
  P.bb  = (const float*)d_in[4];
  P.Wf  = (const float*)d_in[5];
  P.bf  = (const float*)d_in[6];
  P.gf  = (const float*)d_in[7];
  P.bef = (const float*)d_in[8];
  P.Wd  = (const float*)d_in[9];
  P.bd  = (const float*)d_in[10];
  P.gd  = (const float*)d_in[11];
  P.bed = (const float*)d_in[12];
  P.Wu  = (const float*)d_in[13];
  P.bu  = (const float*)d_in[14];
  P.gu  = (const float*)d_in[15];
  P.beu = (const float*)d_in[16];
  P.gs  = (const float*)d_in[17];
  P.bes = (const float*)d_in[18];
  P.w1  = (const float*)d_in[19];
  P.b1  = (const float*)d_in[20];
  P.w2  = (const float*)d_in[21];
  P.b2  = (const float*)d_in[22];
  P.Wh  = (const float*)d_in[23];
  P.bh  = (const float*)d_in[24];
  P.out = (float*)d_out;

  f16* wf16 = (f16*)d_ws;
  hipLaunchKernelGGL(wf16_kernel, dim3(320), dim3(512), 0, stream, P.Wf, wf16);
  P.wf16 = wf16;

  int B = in_sizes[0] / (T_LEN * DI);
  hipLaunchKernelGGL(ctm_kernel, dim3(B), dim3(512), 0, stream, P);
}